// Round 3
// baseline (4515.587 us; speedup 1.0000x reference)
//
#include <hip/hip_runtime.h>
#include <hip/hip_bf16.h>
#include <math.h>

// Problem constants (reference: HIDDEN=512, B=4, S=2048, BETA=1, 5 iters, 1e-4)
// Round 3: per-tensor dtype DETECTION on device (mixed bf16/fp32 evidence across
// rounds 1-2). Internal pipeline fp32; out dtype = bf16 iff any input is bf16.
#define HH 512
#define BB 4
#define SS 2048
#define NN (BB*SS)                       // 8192 rows total
#define SCALE_F 0.04419417382415922f     // 1/sqrt(512)
#define QR 32                            // query rows per attention block
#define KT 32                            // key rows per tile
#define HP 516                           // padded LDS row stride (floats)
#define THRESH 1e-4f
#define CTL_FLOATS 1024                  // workspace floats reserved for Ctl at ws start

struct Ctl { float sum_d; float sum_o; int iters; int conv; int bf[10]; }; // bf[9] = any-bf16

__device__ __forceinline__ float b2f(unsigned short u) {
    union { unsigned int i; float f; } c; c.i = ((unsigned int)u) << 16; return c.f;
}
__device__ __forceinline__ unsigned short f2b(float f) {
    unsigned int x = __float_as_uint(f);
    unsigned int r = (x + 0x7FFFu + ((x >> 16) & 1u)) >> 16;   // round-to-nearest-even
    return (unsigned short)r;
}
__device__ __forceinline__ float sum4(const float4 v) { return v.x + v.y + v.z + v.w; }
__device__ __forceinline__ void fma4(float4& a, const float4 q, const float4 k) {
    a.x += q.x*k.x; a.y += q.y*k.y; a.z += q.z*k.z; a.w += q.w*k.w;
}
__device__ __forceinline__ void fma4s(float4& a, const float p, const float4 k) {
    a.x += p*k.x; a.y += p*k.y; a.z += p*k.z; a.w += p*k.w;
}

// One block per input tensor. Reads first min(n,4096) ushorts (always in-bounds for
// both dtypes since n is the ELEMENT count). bf16 data: exponent field never <32 or
// >=224. fp32 data: mantissa-low ushorts have uniform exponents -> ~n/8 hits.
__global__ __launch_bounds__(256) void detect_dtypes(
        const void* p0, const void* p1, const void* p2, const void* p3, const void* p4,
        const void* p5, const void* p6, const void* p7, const void* p8, Ctl* sc)
{
    const void* ps[9] = {p0,p1,p2,p3,p4,p5,p6,p7,p8};
    const int   ns[9] = {NN*HH, HH*HH, HH, HH*HH, HH, HH*HH, HH, HH*HH, HH};
    const int i = blockIdx.x;
    const unsigned short* u = (const unsigned short*)ps[i];
    const int n = ns[i] < 4096 ? ns[i] : 4096;
    __shared__ int cnt;
    if (threadIdx.x == 0) cnt = 0;
    __syncthreads();
    int c = 0;
    for (int j = threadIdx.x; j < n; j += 256) {
        const int e = (u[j] >> 7) & 0xFF;
        if (e < 32 || e >= 224) ++c;
    }
    if (c) atomicAdd(&cnt, c);
    __syncthreads();
    if (threadIdx.x == 0) sc->bf[i] = (cnt * 16 < n) ? 1 : 0;   // few "impossible" exps -> bf16
}

__global__ __launch_bounds__(64) void init_flags(Ctl* sc) {
    if (threadIdx.x == 0) {
        sc->iters = 0; sc->conv = 0; sc->sum_d = 0.f; sc->sum_o = 0.f;
        int any = 0;
        for (int i = 0; i < 9; ++i) any |= sc->bf[i];
        sc->bf[9] = any;
    }
}

__global__ __launch_bounds__(64) void prep_iter(Ctl* sc) {
    if (threadIdx.x == 0) { sc->sum_d = 0.f; sc->sum_o = 0.f; }
}

// C[m,n] = sum_k X[m,k]*W[n,k] + bias[n]   (x @ W^T + b), fp32 compute.
// Dtype of X/W/bias resolved at runtime from sc->bf[idx] (idx<0 => fp32 workspace).
// outMode: 0 => fp32 workspace; 1 => external out, bf16 iff sc->bf[9].
__global__ __launch_bounds__(256) void proj_gemm(const void* __restrict__ Xv, int xIdx,
                                                 const void* __restrict__ Wv, int wIdx,
                                                 const void* __restrict__ biasv, int bIdx,
                                                 void* __restrict__ outv, int outMode,
                                                 const Ctl* __restrict__ sc)
{
    __shared__ float As[16][65];   // As[k][m]
    __shared__ float Bs[16][65];   // Bs[k][n]
    const bool xbf = (xIdx >= 0) && (sc->bf[xIdx] != 0);
    const bool wbf = (sc->bf[wIdx] != 0);
    const bool bbf = (sc->bf[bIdx] != 0);
    const bool obf = (outMode != 0) && (sc->bf[9] != 0);

    const int tid = threadIdx.x;
    const int m0 = blockIdx.x * 64, n0 = blockIdx.y * 64;
    const int tx = tid & 15, ty = tid >> 4;
    const int lr = tid >> 2;            // 0..63 staging row
    const int lk = (tid & 3) * 4;       // 0,4,8,12 staging k offset

    float acc[4][4] = {};

    for (int k0 = 0; k0 < HH; k0 += 16) {
        float a4[4], b4[4];
        if (xbf) {
            const ushort4 t = *(const ushort4*)((const unsigned short*)Xv + (size_t)(m0 + lr)*HH + k0 + lk);
            a4[0] = b2f(t.x); a4[1] = b2f(t.y); a4[2] = b2f(t.z); a4[3] = b2f(t.w);
        } else {
            const float4 t = *(const float4*)((const float*)Xv + (size_t)(m0 + lr)*HH + k0 + lk);
            a4[0] = t.x; a4[1] = t.y; a4[2] = t.z; a4[3] = t.w;
        }
        if (wbf) {
            const ushort4 t = *(const ushort4*)((const unsigned short*)Wv + (size_t)(n0 + lr)*HH + k0 + lk);
            b4[0] = b2f(t.x); b4[1] = b2f(t.y); b4[2] = b2f(t.z); b4[3] = b2f(t.w);
        } else {
            const float4 t = *(const float4*)((const float*)Wv + (size_t)(n0 + lr)*HH + k0 + lk);
            b4[0] = t.x; b4[1] = t.y; b4[2] = t.z; b4[3] = t.w;
        }
        __syncthreads();   // previous compute done before overwriting tiles
        As[lk+0][lr] = a4[0]; As[lk+1][lr] = a4[1]; As[lk+2][lr] = a4[2]; As[lk+3][lr] = a4[3];
        Bs[lk+0][lr] = b4[0]; Bs[lk+1][lr] = b4[1]; Bs[lk+2][lr] = b4[2]; Bs[lk+3][lr] = b4[3];
        __syncthreads();
        #pragma unroll
        for (int k = 0; k < 16; ++k) {
            float a[4], b[4];
            #pragma unroll
            for (int i = 0; i < 4; ++i) a[i] = As[k][ty + 16*i];
            #pragma unroll
            for (int j = 0; j < 4; ++j) b[j] = Bs[k][tx + 16*j];
            #pragma unroll
            for (int i = 0; i < 4; ++i)
                #pragma unroll
                for (int j = 0; j < 4; ++j)
                    acc[i][j] += a[i] * b[j];
        }
    }
    float bb[4];
    #pragma unroll
    for (int j = 0; j < 4; ++j) {
        const int idx = n0 + tx + 16*j;
        bb[j] = bbf ? b2f(((const unsigned short*)biasv)[idx]) : ((const float*)biasv)[idx];
    }
    #pragma unroll
    for (int i = 0; i < 4; ++i) {
        const size_t row = (size_t)(m0 + ty + 16*i) * HH;
        #pragma unroll
        for (int j = 0; j < 4; ++j) {
            const float v = acc[i][j] + bb[j];
            const size_t idx = row + n0 + tx + 16*j;
            if (obf) ((unsigned short*)outv)[idx] = f2b(v);
            else     ((float*)outv)[idx] = v;
        }
    }
}

// Fused flash-style attention (fp32 workspace I/O). Per block: batch b, QR=32 query rows.
// FINAL=false: out = softmax(state K^T * scale) K, accumulates ||new-old||^2, ||old||^2.
// FINAL=true : out = softmax(state K^T * scale) V  (V restaged into K buffer per tile).
template<bool FINAL>
__global__ __launch_bounds__(256) void attn_kernel(const float* __restrict__ Qst,
                                                   const float* __restrict__ Keys,
                                                   const float* __restrict__ Vals,
                                                   float* __restrict__ Out,
                                                   Ctl* sc)
{
    if constexpr (!FINAL) { if (sc->conv) return; }   // uniform early-out, before any barrier

    __shared__ float Qs[QR][HP];
    __shared__ float Ks[KT][HP];
    __shared__ float Ps[QR][KT + 1];
    __shared__ float redd[4], redo[4];

    const int tid = threadIdx.x;
    const int b  = blockIdx.y;
    const int q0 = blockIdx.x * QR;
    const float* Qb = Qst + ((size_t)b*SS + q0) * HH;
    const float* Kb = Keys + (size_t)b*SS*HH;
    const float* Vb = Vals + (size_t)b*SS*HH;

    const int qi = tid >> 4;          // 0..15 -> rows 2qi, 2qi+1
    const int ki = tid & 15;          // 0..15 -> score cols ki, ki+16 ; O col base 4*ki
    const int lrow = tid >> 4;        // staging: 0..15
    const int lcol = (tid & 15) * 4;  // staging: 0..60

    // stage Q tile (32 x 512)
    #pragma unroll
    for (int rr = 0; rr < 2; ++rr)
        #pragma unroll
        for (int cc = 0; cc < 8; ++cc) {
            const int r = lrow + 16*rr, c = lcol + 64*cc;
            *(float4*)&Qs[r][c] = *(const float4*)(Qb + (size_t)r*HH + c);
        }

    float4 O[2][8];
    #pragma unroll
    for (int r = 0; r < 2; ++r)
        #pragma unroll
        for (int j = 0; j < 8; ++j) O[r][j] = make_float4(0.f, 0.f, 0.f, 0.f);
    float mrow[2] = {-INFINITY, -INFINITY};
    float lsum[2] = {0.f, 0.f};

    __syncthreads();

    for (int kt = 0; kt < SS/KT; ++kt) {
        // stage K tile (32 x 512)
        const float* Kt = Kb + (size_t)kt*KT*HH;
        #pragma unroll
        for (int rr = 0; rr < 2; ++rr)
            #pragma unroll
            for (int cc = 0; cc < 8; ++cc) {
                const int r = lrow + 16*rr, c = lcol + 64*cc;
                *(float4*)&Ks[r][c] = *(const float4*)(Kt + (size_t)r*HH + c);
            }
        __syncthreads();

        // phase 1: S[2 rows][cols {ki, ki+16}]
        float4 a00 = make_float4(0,0,0,0), a01 = a00, a10 = a00, a11 = a00;
        #pragma unroll 4
        for (int h = 0; h < HH; h += 4) {
            const float4 q0v = *(const float4*)&Qs[2*qi  ][h];
            const float4 q1v = *(const float4*)&Qs[2*qi+1][h];
            const float4 k0v = *(const float4*)&Ks[ki   ][h];
            const float4 k1v = *(const float4*)&Ks[ki+16][h];
            fma4(a00, q0v, k0v); fma4(a01, q0v, k1v);
            fma4(a10, q1v, k0v); fma4(a11, q1v, k1v);
        }
        float s[2][2];
        s[0][0] = sum4(a00)*SCALE_F; s[0][1] = sum4(a01)*SCALE_F;
        s[1][0] = sum4(a10)*SCALE_F; s[1][1] = sum4(a11)*SCALE_F;

        // online softmax per row (16 lanes per row-group, width-16 shuffles)
        #pragma unroll
        for (int r = 0; r < 2; ++r) {
            float mt = fmaxf(s[r][0], s[r][1]);
            #pragma unroll
            for (int msk = 1; msk < 16; msk <<= 1) mt = fmaxf(mt, __shfl_xor(mt, msk, 16));
            const float mnew = fmaxf(mrow[r], mt);
            const float p0 = __expf(s[r][0] - mnew);
            const float p1 = __expf(s[r][1] - mnew);
            float psum = p0 + p1;
            #pragma unroll
            for (int msk = 1; msk < 16; msk <<= 1) psum += __shfl_xor(psum, msk, 16);
            const float alpha = __expf(mrow[r] - mnew);
            lsum[r] = lsum[r]*alpha + psum;
            mrow[r] = mnew;
            #pragma unroll
            for (int j = 0; j < 8; ++j) {
                O[r][j].x *= alpha; O[r][j].y *= alpha; O[r][j].z *= alpha; O[r][j].w *= alpha;
            }
            Ps[2*qi + r][ki]      = p0;
            Ps[2*qi + r][ki + 16] = p1;
        }
        __syncthreads();   // Ps visible; Ks safe to overwrite in FINAL

        if constexpr (FINAL) {
            const float* Vt = Vb + (size_t)kt*KT*HH;
            #pragma unroll
            for (int rr = 0; rr < 2; ++rr)
                #pragma unroll
                for (int cc = 0; cc < 8; ++cc) {
                    const int r = lrow + 16*rr, c = lcol + 64*cc;
                    *(float4*)&Ks[r][c] = *(const float4*)(Vt + (size_t)r*HH + c);
                }
            __syncthreads();
        }

        // phase 2: O[r][h] += sum_t P[r][t] * Ks[t][h]
        #pragma unroll 2
        for (int t = 0; t < KT; ++t) {
            const float pa = Ps[2*qi  ][t];
            const float pb = Ps[2*qi+1][t];
            #pragma unroll
            for (int j = 0; j < 8; ++j) {
                const float4 kv = *(const float4*)&Ks[t][64*j + 4*ki];
                fma4s(O[0][j], pa, kv);
                fma4s(O[1][j], pb, kv);
            }
        }
        __syncthreads();   // before next tile restages Ks / rewrites Ps
    }

    // epilogue: normalize, store, (iteration) accumulate norms
    float pd = 0.f, po = 0.f;
    float* Ob = Out + ((size_t)b*SS + q0) * HH;
    #pragma unroll
    for (int r = 0; r < 2; ++r) {
        const float invl = 1.0f / lsum[r];
        const int row = 2*qi + r;
        #pragma unroll
        for (int j = 0; j < 8; ++j) {
            const int c = 64*j + 4*ki;
            float4 nv;
            nv.x = O[r][j].x * invl; nv.y = O[r][j].y * invl;
            nv.z = O[r][j].z * invl; nv.w = O[r][j].w * invl;
            if constexpr (!FINAL) {
                const float4 ov = *(const float4*)&Qs[row][c];
                const float dx = nv.x-ov.x, dy = nv.y-ov.y, dz = nv.z-ov.z, dw = nv.w-ov.w;
                pd += dx*dx + dy*dy + dz*dz + dw*dw;
                po += ov.x*ov.x + ov.y*ov.y + ov.z*ov.z + ov.w*ov.w;
            }
            *(float4*)(Ob + (size_t)row*HH + c) = nv;
        }
    }
    if constexpr (!FINAL) {
        #pragma unroll
        for (int msk = 1; msk < 64; msk <<= 1) {
            pd += __shfl_xor(pd, msk, 64);
            po += __shfl_xor(po, msk, 64);
        }
        const int wid = tid >> 6;
        if ((tid & 63) == 0) { redd[wid] = pd; redo[wid] = po; }
        __syncthreads();
        if (tid == 0) {
            atomicAdd(&sc->sum_d, redd[0] + redd[1] + redd[2] + redd[3]);
            atomicAdd(&sc->sum_o, redo[0] + redo[1] + redo[2] + redo[3]);
        }
    }
}

__global__ __launch_bounds__(256) void commit_state(float* __restrict__ state,
                                                    const float* __restrict__ newst,
                                                    const Ctl* sc)
{
    if (sc->conv) return;
    const size_t i = ((size_t)blockIdx.x * 256 + threadIdx.x) * 4;
    *(float4*)(state + i) = *(const float4*)(newst + i);
}

__global__ __launch_bounds__(64) void flag_update(Ctl* sc) {
    if (threadIdx.x != 0) return;
    if (sc->conv) return;
    sc->iters += 1;
    const float delta = sqrtf(sc->sum_d) / (sqrtf(sc->sum_o) + 1e-8f);
    if (delta < THRESH) sc->conv = 1;
}

__global__ __launch_bounds__(64) void write_scalars(const Ctl* sc, void* outv) {
    if (threadIdx.x != 0) return;
    if (sc->bf[9]) {
        unsigned short* o = (unsigned short*)outv;
        o[(size_t)NN*HH]     = f2b((float)sc->iters);
        o[(size_t)NN*HH + 1] = f2b(sc->conv ? 1.0f : 0.0f);
    } else {
        float* o = (float*)outv;
        o[(size_t)NN*HH]     = (float)sc->iters;
        o[(size_t)NN*HH + 1] = sc->conv ? 1.0f : 0.0f;
    }
}

extern "C" void kernel_launch(void* const* d_in, const int* in_sizes, int n_in,
                              void* d_out, int out_size, void* d_ws, size_t ws_size,
                              hipStream_t stream)
{
    const void* x  = d_in[0];
    const void* Wq = d_in[1];
    const void* bq = d_in[2];
    const void* Wk = d_in[3];
    const void* bk = d_in[4];
    const void* Wv = d_in[5];
    const void* bv = d_in[6];
    const void* Wo = d_in[7];
    const void* bo = d_in[8];

    Ctl* sc      = (Ctl*)d_ws;                          // control block at ws start
    float* base  = (float*)d_ws + CTL_FLOATS;
    float* state = base;                                // [NN,HH] Q -> hopfield state
    float* keys  = state + (size_t)NN*HH;               // [NN,HH]
    float* vals  = keys  + (size_t)NN*HH;               // [NN,HH]
    float* newst = vals  + (size_t)NN*HH;               // [NN,HH] new state / readout

    const dim3 pgrid(NN/64, HH/64);   // 128 x 8
    const dim3 agrid(SS/QR, BB);      // 64 x 4

    detect_dtypes<<<9, 256, 0, stream>>>(x, Wq, bq, Wk, bk, Wv, bv, Wo, bo, sc);
    init_flags<<<1, 64, 0, stream>>>(sc);

    proj_gemm<<<pgrid, 256, 0, stream>>>(x, 0, Wq, 1, bq, 2, state, 0, sc);
    proj_gemm<<<pgrid, 256, 0, stream>>>(x, 0, Wk, 3, bk, 4, keys,  0, sc);
    proj_gemm<<<pgrid, 256, 0, stream>>>(x, 0, Wv, 5, bv, 6, vals,  0, sc);

    for (int it = 0; it < 5; ++it) {
        prep_iter<<<1, 64, 0, stream>>>(sc);
        attn_kernel<false><<<agrid, 256, 0, stream>>>(state, keys, vals, newst, sc);
        commit_state<<<(NN*HH)/1024, 256, 0, stream>>>(state, newst, sc);
        flag_update<<<1, 64, 0, stream>>>(sc);
    }

    attn_kernel<true><<<agrid, 256, 0, stream>>>(state, keys, vals, newst, sc);
    proj_gemm<<<pgrid, 256, 0, stream>>>(newst, -1, Wo, 7, bo, 8, d_out, 1, sc);
    if (out_size >= (int)((size_t)NN*HH + 2))
        write_scalars<<<1, 64, 0, stream>>>(sc, d_out);
}

// Round 4
// 2780.139 us; speedup vs baseline: 1.6242x; 1.6242x over previous
//
#include <hip/hip_runtime.h>
#include <hip/hip_bf16.h>
#include <math.h>

// TrueHopfieldLayer: HIDDEN=512, B=4, S=2048, 5 iters, thresh 1e-4.
// Round 4: MFMA everywhere. Iteration attention uses split-bf16 (hi+lo, ~16-bit)
// so the fp32 convergence delta tracks the np reference (ref converges at iter 4).
#define HH 512
#define BB 4
#define SS 2048
#define NN (BB*SS)
#define SCALE_F 0.04419417382415922f     // 1/sqrt(512)
#define THRESH 1e-4f
#define CTL_FLOATS 1024

typedef __attribute__((ext_vector_type(8))) short bf16x8;
typedef __attribute__((ext_vector_type(4))) short bf16x4;
typedef __attribute__((ext_vector_type(4))) float f32x4;

struct Ctl { float sum_d; float sum_o; int iters; int conv; int bf[10]; }; // bf[9]=any

__device__ __forceinline__ float b2f(unsigned short u) {
    union { unsigned int i; float f; } c; c.i = ((unsigned int)u) << 16; return c.f;
}
__device__ __forceinline__ unsigned short f2b(float f) {
    unsigned int x = __float_as_uint(f);
    unsigned int r = (x + 0x7FFFu + ((x >> 16) & 1u)) >> 16;   // RNE
    return (unsigned short)r;
}
__device__ __forceinline__ void splitf(float x, unsigned short& h, unsigned short& l) {
    h = f2b(x);
    l = f2b(x - b2f(h));
}
__device__ __forceinline__ f32x4 MF(bf16x8 a, bf16x8 b, f32x4 c) {
    return __builtin_amdgcn_mfma_f32_16x16x32_bf16(a, b, c, 0, 0, 0);
}

// ---------- dtype detection (round-3, proven) ----------
__global__ __launch_bounds__(256) void detect_dtypes(
        const void* p0, const void* p1, const void* p2, const void* p3, const void* p4,
        const void* p5, const void* p6, const void* p7, const void* p8, Ctl* sc)
{
    const void* ps[9] = {p0,p1,p2,p3,p4,p5,p6,p7,p8};
    const int   ns[9] = {NN*HH, HH*HH, HH, HH*HH, HH, HH*HH, HH, HH*HH, HH};
    const int i = blockIdx.x;
    const unsigned short* u = (const unsigned short*)ps[i];
    const int n = ns[i] < 4096 ? ns[i] : 4096;
    __shared__ int cnt;
    if (threadIdx.x == 0) cnt = 0;
    __syncthreads();
    int c = 0;
    for (int j = threadIdx.x; j < n; j += 256) {
        const int e = (u[j] >> 7) & 0xFF;
        if (e < 32 || e >= 224) ++c;
    }
    if (c) atomicAdd(&cnt, c);
    __syncthreads();
    if (threadIdx.x == 0) sc->bf[i] = (cnt * 16 < n) ? 1 : 0;
}

__global__ __launch_bounds__(64) void init_flags(Ctl* sc) {
    if (threadIdx.x == 0) {
        sc->iters = 0; sc->conv = 0; sc->sum_d = 0.f; sc->sum_o = 0.f;
        int any = 0;
        for (int i = 0; i < 9; ++i) any |= sc->bf[i];
        sc->bf[9] = any;
    }
}
__global__ __launch_bounds__(64) void prep_iter(Ctl* sc) {
    if (threadIdx.x == 0) { sc->sum_d = 0.f; sc->sum_o = 0.f; }
}

// ---------- MFMA GEMM: C = X @ W^T + bias ----------
// mode 0: f32 out (state). mode 1: external out (bf16/f32 per bf[9]).
// mode 2: split out -> outH/outL bf16 planes (keys/vals).
// X/W loaded per runtime dtype flags; split-bf16 products only where needed.
__global__ __launch_bounds__(256) void mfma_gemm(
    const void* __restrict__ Xv, int xIdx,
    const void* __restrict__ Wv, int wIdx,
    const void* __restrict__ Bv, int bIdx,
    float* __restrict__ outF, void* __restrict__ outExt,
    unsigned short* __restrict__ outH, unsigned short* __restrict__ outL,
    int mode, const Ctl* __restrict__ sc)
{
    __shared__ unsigned short Xh[64][72], Xl[64][72], Wh[64][72], Wl[64][72];
    const int tid = threadIdx.x;
    const bool xbf = (xIdx >= 0) && (sc->bf[xIdx] != 0);
    const bool wbf = (sc->bf[wIdx] != 0);
    const bool bbf = (sc->bf[bIdx] != 0);
    const bool obf = (mode == 1) && (sc->bf[9] != 0);
    const bool xs = !xbf, ws = !wbf;   // low-plane products needed?

    const int m0 = blockIdx.x * 64, n0 = blockIdx.y * 64;
    const int lane = tid & 63, w = tid >> 6;
    const int mi = w & 1, ni = w >> 1;
    const int quad = lane >> 4, l16 = lane & 15;
    const int srow = tid >> 2, skb = (tid & 3) * 16;

    f32x4 acc[2][2];
    #pragma unroll
    for (int a = 0; a < 2; ++a)
        #pragma unroll
        for (int bq = 0; bq < 2; ++bq) acc[a][bq] = (f32x4){0.f, 0.f, 0.f, 0.f};

    for (int kc = 0; kc < HH; kc += 64) {
        __syncthreads();
        // stage X tile row
        {
            float v[16];
            if (xbf) {
                const unsigned short* p = (const unsigned short*)Xv + (size_t)(m0 + srow)*HH + kc + skb;
                #pragma unroll
                for (int i = 0; i < 4; ++i) {
                    ushort4 t = *(const ushort4*)(p + 4*i);
                    v[4*i]=b2f(t.x); v[4*i+1]=b2f(t.y); v[4*i+2]=b2f(t.z); v[4*i+3]=b2f(t.w);
                }
            } else {
                const float* p = (const float*)Xv + (size_t)(m0 + srow)*HH + kc + skb;
                #pragma unroll
                for (int i = 0; i < 4; ++i) {
                    float4 t = *(const float4*)(p + 4*i);
                    v[4*i]=t.x; v[4*i+1]=t.y; v[4*i+2]=t.z; v[4*i+3]=t.w;
                }
            }
            #pragma unroll
            for (int i = 0; i < 4; ++i) {
                unsigned short h[4], l[4];
                #pragma unroll
                for (int j = 0; j < 4; ++j) splitf(v[4*i+j], h[j], l[j]);
                *(ushort4*)&Xh[srow][skb + 4*i] = make_ushort4(h[0], h[1], h[2], h[3]);
                if (xs) *(ushort4*)&Xl[srow][skb + 4*i] = make_ushort4(l[0], l[1], l[2], l[3]);
            }
        }
        // stage W tile row
        {
            float v[16];
            if (wbf) {
                const unsigned short* p = (const unsigned short*)Wv + (size_t)(n0 + srow)*HH + kc + skb;
                #pragma unroll
                for (int i = 0; i < 4; ++i) {
                    ushort4 t = *(const ushort4*)(p + 4*i);
                    v[4*i]=b2f(t.x); v[4*i+1]=b2f(t.y); v[4*i+2]=b2f(t.z); v[4*i+3]=b2f(t.w);
                }
            } else {
                const float* p = (const float*)Wv + (size_t)(n0 + srow)*HH + kc + skb;
                #pragma unroll
                for (int i = 0; i < 4; ++i) {
                    float4 t = *(const float4*)(p + 4*i);
                    v[4*i]=t.x; v[4*i+1]=t.y; v[4*i+2]=t.z; v[4*i+3]=t.w;
                }
            }
            #pragma unroll
            for (int i = 0; i < 4; ++i) {
                unsigned short h[4], l[4];
                #pragma unroll
                for (int j = 0; j < 4; ++j) splitf(v[4*i+j], h[j], l[j]);
                *(ushort4*)&Wh[srow][skb + 4*i] = make_ushort4(h[0], h[1], h[2], h[3]);
                if (ws) *(ushort4*)&Wl[srow][skb + 4*i] = make_ushort4(l[0], l[1], l[2], l[3]);
            }
        }
        __syncthreads();
        #pragma unroll
        for (int d = 0; d < 2; ++d) {
            const int kl = 32*d + quad*8;
            #pragma unroll
            for (int mt = 0; mt < 2; ++mt) {
                const int xr = 32*mi + 16*mt + l16;
                bf16x8 ah = *(const bf16x8*)&Xh[xr][kl];
                bf16x8 al;
                if (xs) al = *(const bf16x8*)&Xl[xr][kl];
                #pragma unroll
                for (int nt = 0; nt < 2; ++nt) {
                    const int wr = 32*ni + 16*nt + l16;
                    bf16x8 bh = *(const bf16x8*)&Wh[wr][kl];
                    acc[mt][nt] = MF(ah, bh, acc[mt][nt]);
                    if (xs) acc[mt][nt] = MF(al, bh, acc[mt][nt]);
                    if (ws) {
                        bf16x8 bl = *(const bf16x8*)&Wl[wr][kl];
                        acc[mt][nt] = MF(ah, bl, acc[mt][nt]);
                    }
                }
            }
        }
    }
    // epilogue
    #pragma unroll
    for (int nt = 0; nt < 2; ++nt) {
        const int col = n0 + 32*ni + 16*nt + l16;
        const float bv = bbf ? b2f(((const unsigned short*)Bv)[col]) : ((const float*)Bv)[col];
        #pragma unroll
        for (int mt = 0; mt < 2; ++mt)
            #pragma unroll
            for (int e = 0; e < 4; ++e) {
                const int row = m0 + 32*mi + 16*mt + quad*4 + e;
                const float vv = acc[mt][nt][e] + bv;
                const size_t idx = (size_t)row*HH + col;
                if (mode == 0) outF[idx] = vv;
                else if (mode == 1) {
                    if (obf) ((unsigned short*)outExt)[idx] = f2b(vv);
                    else     ((float*)outExt)[idx] = vv;
                } else {
                    unsigned short h, l; splitf(vv, h, l);
                    outH[idx] = h; outL[idx] = l;
                }
            }
    }
}

// ---------- MFMA flash attention, split-bf16 precision ----------
// Per block: batch b, 32 query rows. Steps of 32 keys; online softmax.
// Scores: sh*kh + sl*kh + sh*kl.  PV: Ph*Vh + Pl*Vh + Ph*Vl (V=keys for iters).
// FINAL=false also accumulates ||new-old||^2 and ||old||^2 (fp32, vs fp32 state).
template<bool FINAL>
__global__ __launch_bounds__(256) void mfma_attn(
    const float* __restrict__ Qst,
    const unsigned short* __restrict__ KH, const unsigned short* __restrict__ KL,
    const unsigned short* __restrict__ VH, const unsigned short* __restrict__ VL,
    float* __restrict__ Out, Ctl* sc)
{
    if constexpr (!FINAL) { if (sc->conv) return; }

    __shared__ unsigned short SHh[32][520], SHl[32][520];   // state planes
    __shared__ unsigned short KBH[32][264], KBL[32][264];   // scores keys chunk (256 hid)
    __shared__ unsigned short KTH[128][36], KTL[128][36];   // PV transposed chunk
    __shared__ float Sld[32][33];
    __shared__ unsigned short Pth[32][40], Ptl[32][40];
    __shared__ float mld[32], lld[32], ald[32];
    __shared__ float redd[4], redo[4];

    const int tid = threadIdx.x;
    const int lane = tid & 63, w = tid >> 6;
    const int quad = lane >> 4, l16 = lane & 15;
    const int b = blockIdx.y, q0 = blockIdx.x * 32;
    const int r = w & 1, s = w >> 1;

    // stage + split state tile (32 x 512)
    {
        const int row = tid >> 3, hb = (tid & 7) * 64;
        const float* src = Qst + ((size_t)(b*SS) + q0 + row)*HH + hb;
        #pragma unroll
        for (int i = 0; i < 16; ++i) {
            float4 v = *(const float4*)(src + 4*i);
            unsigned short h[4], l[4];
            splitf(v.x, h[0], l[0]); splitf(v.y, h[1], l[1]);
            splitf(v.z, h[2], l[2]); splitf(v.w, h[3], l[3]);
            *(ushort4*)&SHh[row][hb + 4*i] = make_ushort4(h[0], h[1], h[2], h[3]);
            *(ushort4*)&SHl[row][hb + 4*i] = make_ushort4(l[0], l[1], l[2], l[3]);
        }
        if (tid < 32) { mld[tid] = -INFINITY; lld[tid] = 0.f; }
    }

    f32x4 O[4][4];
    #pragma unroll
    for (int c = 0; c < 4; ++c)
        #pragma unroll
        for (int nt = 0; nt < 4; ++nt) O[c][nt] = (f32x4){0.f, 0.f, 0.f, 0.f};

    const unsigned short* KHb = KH + (size_t)(b*SS)*HH;
    const unsigned short* KLb = KL + (size_t)(b*SS)*HH;
    const unsigned short* VHb = VH + (size_t)(b*SS)*HH;
    const unsigned short* VLb = VL + (size_t)(b*SS)*HH;

    for (int kt = 0; kt < SS/32; ++kt) {
        f32x4 sacc = (f32x4){0.f, 0.f, 0.f, 0.f};
        // ---- scores over 2 hidden chunks of 256 ----
        #pragma unroll
        for (int cc = 0; cc < 2; ++cc) {
            __syncthreads();
            {
                const int key = tid >> 3, hb = (tid & 7) * 32;
                const size_t g = (size_t)(kt*32 + key)*HH + cc*256 + hb;
                #pragma unroll
                for (int i = 0; i < 8; ++i) {
                    *(ushort4*)&KBH[key][hb + 4*i] = *(const ushort4*)(KHb + g + 4*i);
                    *(ushort4*)&KBL[key][hb + 4*i] = *(const ushort4*)(KLb + g + 4*i);
                }
            }
            __syncthreads();
            #pragma unroll
            for (int d = 0; d < 8; ++d) {
                const int ka = 32*d + quad*8;
                bf16x8 ah = *(const bf16x8*)&SHh[16*r + l16][cc*256 + ka];
                bf16x8 al = *(const bf16x8*)&SHl[16*r + l16][cc*256 + ka];
                bf16x8 bh = *(const bf16x8*)&KBH[16*s + l16][ka];
                bf16x8 bl = *(const bf16x8*)&KBL[16*s + l16][ka];
                sacc = MF(ah, bh, sacc);
                sacc = MF(al, bh, sacc);
                sacc = MF(ah, bl, sacc);
            }
        }
        #pragma unroll
        for (int e = 0; e < 4; ++e)
            Sld[16*r + quad*4 + e][16*s + l16] = sacc[e] * SCALE_F;
        __syncthreads();
        // ---- online softmax (8 threads per row) ----
        {
            const int row = tid >> 3, kb = (tid & 7) * 4;
            float sv[4];
            #pragma unroll
            for (int i = 0; i < 4; ++i) sv[i] = Sld[row][kb + i];
            float mt = fmaxf(fmaxf(sv[0], sv[1]), fmaxf(sv[2], sv[3]));
            #pragma unroll
            for (int mk = 1; mk < 8; mk <<= 1) mt = fmaxf(mt, __shfl_xor(mt, mk, 8));
            const float mprev = mld[row];
            const float mnew = fmaxf(mprev, mt);
            float p[4], ps = 0.f;
            #pragma unroll
            for (int i = 0; i < 4; ++i) { p[i] = __expf(sv[i] - mnew); ps += p[i]; }
            #pragma unroll
            for (int mk = 1; mk < 8; mk <<= 1) ps += __shfl_xor(ps, mk, 8);
            const float alpha = __expf(mprev - mnew);
            if ((tid & 7) == 0) { mld[row] = mnew; lld[row] = lld[row]*alpha + ps; ald[row] = alpha; }
            #pragma unroll
            for (int i = 0; i < 4; ++i) {
                unsigned short h, l; splitf(p[i], h, l);
                Pth[row][kb + i] = h; Ptl[row][kb + i] = l;
            }
        }
        __syncthreads();
        // ---- rescale O ----
        float a4[4];
        #pragma unroll
        for (int e = 0; e < 4; ++e) a4[e] = ald[16*r + quad*4 + e];
        #pragma unroll
        for (int c = 0; c < 4; ++c)
            #pragma unroll
            for (int nt = 0; nt < 4; ++nt)
                #pragma unroll
                for (int e = 0; e < 4; ++e) O[c][nt][e] *= a4[e];
        // P fragments (A-layout)
        bf16x8 pah = *(const bf16x8*)&Pth[16*r + l16][quad*8];
        bf16x8 pal = *(const bf16x8*)&Ptl[16*r + l16][quad*8];
        // ---- PV over 4 hidden chunks of 128 ----
        #pragma unroll
        for (int c = 0; c < 4; ++c) {
            if (c) __syncthreads();
            {   // transpose-stage: 2 keys x 8 hidden per thread, paired b32 writes
                const int kp = (tid & 15) * 2, g = tid >> 4;
                const size_t g0 = (size_t)(kt*32 + kp)*HH + c*128 + g*8;
                ushort4 h0a = *(const ushort4*)(VHb + g0);
                ushort4 h0b = *(const ushort4*)(VHb + g0 + 4);
                ushort4 h1a = *(const ushort4*)(VHb + g0 + HH);
                ushort4 h1b = *(const ushort4*)(VHb + g0 + HH + 4);
                ushort4 l0a = *(const ushort4*)(VLb + g0);
                ushort4 l0b = *(const ushort4*)(VLb + g0 + 4);
                ushort4 l1a = *(const ushort4*)(VLb + g0 + HH);
                ushort4 l1b = *(const ushort4*)(VLb + g0 + HH + 4);
                const unsigned short* h0 = (const unsigned short*)&h0a;  // h0a,h0b contiguous? no — index separately
                unsigned short H0[8] = {h0a.x,h0a.y,h0a.z,h0a.w,h0b.x,h0b.y,h0b.z,h0b.w};
                unsigned short H1[8] = {h1a.x,h1a.y,h1a.z,h1a.w,h1b.x,h1b.y,h1b.z,h1b.w};
                unsigned short L0[8] = {l0a.x,l0a.y,l0a.z,l0a.w,l0b.x,l0b.y,l0b.z,l0b.w};
                unsigned short L1[8] = {l1a.x,l1a.y,l1a.z,l1a.w,l1b.x,l1b.y,l1b.z,l1b.w};
                (void)h0;
                #pragma unroll
                for (int j = 0; j < 8; ++j) {
                    *(unsigned int*)&KTH[g*8 + j][kp] = (unsigned)H0[j] | ((unsigned)H1[j] << 16);
                    *(unsigned int*)&KTL[g*8 + j][kp] = (unsigned)L0[j] | ((unsigned)L1[j] << 16);
                }
            }
            __syncthreads();
            #pragma unroll
            for (int nt = 0; nt < 4; ++nt) {
                const int hr = 64*s + 16*nt + l16;
                bf16x4 t0 = *(const bf16x4*)&KTH[hr][quad*8];
                bf16x4 t1 = *(const bf16x4*)&KTH[hr][quad*8 + 4];
                bf16x4 u0 = *(const bf16x4*)&KTL[hr][quad*8];
                bf16x4 u1 = *(const bf16x4*)&KTL[hr][quad*8 + 4];
                bf16x8 bh, bl;
                bh[0]=t0[0]; bh[1]=t0[1]; bh[2]=t0[2]; bh[3]=t0[3];
                bh[4]=t1[0]; bh[5]=t1[1]; bh[6]=t1[2]; bh[7]=t1[3];
                bl[0]=u0[0]; bl[1]=u0[1]; bl[2]=u0[2]; bl[3]=u0[3];
                bl[4]=u1[0]; bl[5]=u1[1]; bl[6]=u1[2]; bl[7]=u1[3];
                O[c][nt] = MF(pah, bh, O[c][nt]);
                O[c][nt] = MF(pal, bh, O[c][nt]);
                O[c][nt] = MF(pah, bl, O[c][nt]);
            }
        }
    }
    // ---- epilogue: normalize, store, delta ----
    float inv[4];
    #pragma unroll
    for (int e = 0; e < 4; ++e) inv[e] = 1.0f / lld[16*r + quad*4 + e];
    float pd = 0.f, po = 0.f;
    #pragma unroll
    for (int c = 0; c < 4; ++c)
        #pragma unroll
        for (int nt = 0; nt < 4; ++nt)
            #pragma unroll
            for (int e = 0; e < 4; ++e) {
                const int row = 16*r + quad*4 + e;
                const int h = 128*c + 64*s + 16*nt + l16;
                const float nv = O[c][nt][e] * inv[e];
                const size_t idx = ((size_t)(b*SS) + q0 + row)*HH + h;
                if constexpr (!FINAL) {
                    const float old = Qst[idx];
                    const float d = nv - old;
                    pd += d*d; po += old*old;
                }
                Out[idx] = nv;
            }
    if constexpr (!FINAL) {
        #pragma unroll
        for (int mk = 1; mk < 64; mk <<= 1) {
            pd += __shfl_xor(pd, mk, 64);
            po += __shfl_xor(po, mk, 64);
        }
        if (lane == 0) { redd[w] = pd; redo[w] = po; }
        __syncthreads();
        if (tid == 0) {
            atomicAdd(&sc->sum_d, redd[0] + redd[1] + redd[2] + redd[3]);
            atomicAdd(&sc->sum_o, redo[0] + redo[1] + redo[2] + redo[3]);
        }
    }
}

__global__ __launch_bounds__(256) void commit_state(float* __restrict__ state,
                                                    const float* __restrict__ newst,
                                                    const Ctl* sc)
{
    if (sc->conv) return;
    const size_t i = ((size_t)blockIdx.x * 256 + threadIdx.x) * 4;
    *(float4*)(state + i) = *(const float4*)(newst + i);
}

__global__ __launch_bounds__(64) void flag_update(Ctl* sc) {
    if (threadIdx.x != 0) return;
    if (sc->conv) return;
    sc->iters += 1;
    const float delta = sqrtf(sc->sum_d) / (sqrtf(sc->sum_o) + 1e-8f);
    if (delta < THRESH) sc->conv = 1;
}

__global__ __launch_bounds__(64) void write_scalars(const Ctl* sc, void* outv) {
    if (threadIdx.x != 0) return;
    if (sc->bf[9]) {
        unsigned short* o = (unsigned short*)outv;
        o[(size_t)NN*HH]     = f2b((float)sc->iters);
        o[(size_t)NN*HH + 1] = f2b(sc->conv ? 1.0f : 0.0f);
    } else {
        float* o = (float*)outv;
        o[(size_t)NN*HH]     = (float)sc->iters;
        o[(size_t)NN*HH + 1] = sc->conv ? 1.0f : 0.0f;
    }
}

extern "C" void kernel_launch(void* const* d_in, const int* in_sizes, int n_in,
                              void* d_out, int out_size, void* d_ws, size_t ws_size,
                              hipStream_t stream)
{
    const void* x  = d_in[0];
    const void* Wq = d_in[1];
    const void* bq = d_in[2];
    const void* Wk = d_in[3];
    const void* bk = d_in[4];
    const void* Wv = d_in[5];
    const void* bv = d_in[6];
    const void* Wo = d_in[7];
    const void* bo = d_in[8];

    Ctl* sc = (Ctl*)d_ws;
    float* state = (float*)d_ws + CTL_FLOATS;          // [NN,HH] fp32
    float* newst = state + (size_t)NN*HH;              // [NN,HH] fp32
    unsigned short* keysH = (unsigned short*)(newst + (size_t)NN*HH);
    unsigned short* keysL = keysH + (size_t)NN*HH;
    unsigned short* valsH = keysL + (size_t)NN*HH;
    unsigned short* valsL = valsH + (size_t)NN*HH;     // total ~67.1 MB (proven size)

    const dim3 ggrid(NN/64, HH/64);   // 128 x 8
    const dim3 agrid(SS/32, BB);      // 64 x 4

    detect_dtypes<<<9, 256, 0, stream>>>(x, Wq, bq, Wk, bk, Wv, bv, Wo, bo, sc);
    init_flags<<<1, 64, 0, stream>>>(sc);

    mfma_gemm<<<ggrid, 256, 0, stream>>>(x, 0, Wq, 1, bq, 2, state, nullptr, nullptr, nullptr, 0, sc);
    mfma_gemm<<<ggrid, 256, 0, stream>>>(x, 0, Wk, 3, bk, 4, nullptr, nullptr, keysH, keysL, 2, sc);
    mfma_gemm<<<ggrid, 256, 0, stream>>>(x, 0, Wv, 5, bv, 6, nullptr, nullptr, valsH, valsL, 2, sc);

    for (int it = 0; it < 5; ++it) {
        prep_iter<<<1, 64, 0, stream>>>(sc);
        mfma_attn<false><<<agrid, 256, 0, stream>>>(state, keysH, keysL, keysH, keysL, newst, sc);
        commit_state<<<(NN*HH)/1024, 256, 0, stream>>>(state, newst, sc);
        flag_update<<<1, 64, 0, stream>>>(sc);
    }

    mfma_attn<true><<<agrid, 256, 0, stream>>>(state, keysH, keysL, valsH, valsL, newst, sc);
    mfma_gemm<<<ggrid, 256, 0, stream>>>(newst, -1, Wo, 7, bo, 8, nullptr, d_out, nullptr, nullptr, 1, sc);
    if (out_size >= (int)((size_t)NN*HH + 2))
        write_scalars<<<1, 64, 0, stream>>>(sc, d_out);
}

// Round 6
// 2648.176 us; speedup vs baseline: 1.7052x; 1.0498x over previous
//
#include <hip/hip_runtime.h>
#include <hip/hip_bf16.h>
#include <math.h>

// TrueHopfieldLayer: HIDDEN=512, B=4, S=2048, 5 iters, thresh 1e-4.
// Round 6: round-5 structure with the SHl staging bug fixed (missing +quad*8
// left LDS columns 8..31 mod 32 uninitialized -> NaN bf16 patterns).
#define HH 512
#define BB 4
#define SS 2048
#define NN (BB*SS)
#define SCALE_F 0.04419417382415922f     // 1/sqrt(512)
#define THRESH 1e-4f
#define CTL_FLOATS 1024

typedef __attribute__((ext_vector_type(8))) short bf16x8;
typedef __attribute__((ext_vector_type(4))) float f32x4;

struct Ctl { float sum_d; float sum_o; int iters; int conv; int cur; int bf[10]; };

__device__ __forceinline__ float b2f(unsigned short u) {
    union { unsigned int i; float f; } c; c.i = ((unsigned int)u) << 16; return c.f;
}
__device__ __forceinline__ unsigned short f2b(float f) {
    unsigned int x = __float_as_uint(f);
    unsigned int r = (x + 0x7FFFu + ((x >> 16) & 1u)) >> 16;   // RNE
    return (unsigned short)r;
}
__device__ __forceinline__ void splitf(float x, unsigned short& h, unsigned short& l) {
    h = f2b(x);
    l = f2b(x - b2f(h));
}
__device__ __forceinline__ f32x4 MF(bf16x8 a, bf16x8 b, f32x4 c) {
    return __builtin_amdgcn_mfma_f32_16x16x32_bf16(a, b, c, 0, 0, 0);
}

// ---------- dtype detection (proven) ----------
__global__ __launch_bounds__(256) void detect_dtypes(
        const void* p0, const void* p1, const void* p2, const void* p3, const void* p4,
        const void* p5, const void* p6, const void* p7, const void* p8, Ctl* sc)
{
    const void* ps[9] = {p0,p1,p2,p3,p4,p5,p6,p7,p8};
    const int   ns[9] = {NN*HH, HH*HH, HH, HH*HH, HH, HH*HH, HH, HH*HH, HH};
    const int i = blockIdx.x;
    const unsigned short* u = (const unsigned short*)ps[i];
    const int n = ns[i] < 4096 ? ns[i] : 4096;
    __shared__ int cnt;
    if (threadIdx.x == 0) cnt = 0;
    __syncthreads();
    int c = 0;
    for (int j = threadIdx.x; j < n; j += 256) {
        const int e = (u[j] >> 7) & 0xFF;
        if (e < 32 || e >= 224) ++c;
    }
    if (c) atomicAdd(&cnt, c);
    __syncthreads();
    if (threadIdx.x == 0) sc->bf[i] = (cnt * 16 < n) ? 1 : 0;
}

__global__ __launch_bounds__(64) void init_flags(Ctl* sc) {
    if (threadIdx.x == 0) {
        sc->iters = 0; sc->conv = 0; sc->cur = 0; sc->sum_d = 0.f; sc->sum_o = 0.f;
        int any = 0;
        for (int i = 0; i < 9; ++i) any |= sc->bf[i];
        sc->bf[9] = any;
    }
}

// ---------- MFMA GEMM: C = X @ W^T + bias ----------
// mode 0: fp32 out (Q->state). mode 1: external out (X = state[cur] fp32 when xIdx==-2).
// mode 3: K -> KH,KL row-major + KTH,KTL transposed ([b][h][s]) planes.
// mode 4: V -> transposed planes into dead state buffer buf[1^cur].
__global__ __launch_bounds__(256) void mfma_gemm(
    const void* __restrict__ Xv, int xIdx,
    const void* __restrict__ Wv, int wIdx,
    const void* __restrict__ Bv, int bIdx,
    float* __restrict__ outF, void* __restrict__ outExt,
    unsigned short* __restrict__ pKH, unsigned short* __restrict__ pKL,
    unsigned short* __restrict__ pKTH, unsigned short* __restrict__ pKTL,
    float* __restrict__ S0w, float* __restrict__ S1w,
    int mode, const Ctl* __restrict__ sc)
{
    __shared__ unsigned short Xh[64][72], Xl[64][72], Wh[64][72], Wl[64][72];
    const int tid = threadIdx.x;
    const int cur = sc->cur;
    const void* Xp = (xIdx == -2) ? (const void*)(cur ? S1w : S0w) : Xv;
    const bool xbf = (xIdx >= 0) && (sc->bf[xIdx] != 0);
    const bool wbf = (sc->bf[wIdx] != 0);
    const bool bbf = (sc->bf[bIdx] != 0);
    const bool obf = (mode == 1) && (sc->bf[9] != 0);
    const bool xs = !xbf, ws = !wbf;

    const int m0 = blockIdx.x * 64, n0 = blockIdx.y * 64;
    const int lane = tid & 63, w = tid >> 6;
    const int mi = w & 1, ni = w >> 1;
    const int quad = lane >> 4, l16 = lane & 15;
    const int srow = tid >> 2, skb = (tid & 3) * 16;

    f32x4 acc[2][2];
    #pragma unroll
    for (int a = 0; a < 2; ++a)
        #pragma unroll
        for (int bq = 0; bq < 2; ++bq) acc[a][bq] = (f32x4){0.f, 0.f, 0.f, 0.f};

    for (int kc = 0; kc < HH; kc += 64) {
        __syncthreads();
        {
            float v[16];
            if (xbf) {
                const unsigned short* p = (const unsigned short*)Xp + (size_t)(m0 + srow)*HH + kc + skb;
                #pragma unroll
                for (int i = 0; i < 4; ++i) {
                    ushort4 t = *(const ushort4*)(p + 4*i);
                    v[4*i]=b2f(t.x); v[4*i+1]=b2f(t.y); v[4*i+2]=b2f(t.z); v[4*i+3]=b2f(t.w);
                }
            } else {
                const float* p = (const float*)Xp + (size_t)(m0 + srow)*HH + kc + skb;
                #pragma unroll
                for (int i = 0; i < 4; ++i) {
                    float4 t = *(const float4*)(p + 4*i);
                    v[4*i]=t.x; v[4*i+1]=t.y; v[4*i+2]=t.z; v[4*i+3]=t.w;
                }
            }
            #pragma unroll
            for (int i = 0; i < 4; ++i) {
                unsigned short h[4], l[4];
                #pragma unroll
                for (int j = 0; j < 4; ++j) splitf(v[4*i+j], h[j], l[j]);
                *(ushort4*)&Xh[srow][skb + 4*i] = make_ushort4(h[0], h[1], h[2], h[3]);
                if (xs) *(ushort4*)&Xl[srow][skb + 4*i] = make_ushort4(l[0], l[1], l[2], l[3]);
            }
        }
        {
            float v[16];
            if (wbf) {
                const unsigned short* p = (const unsigned short*)Wv + (size_t)(n0 + srow)*HH + kc + skb;
                #pragma unroll
                for (int i = 0; i < 4; ++i) {
                    ushort4 t = *(const ushort4*)(p + 4*i);
                    v[4*i]=b2f(t.x); v[4*i+1]=b2f(t.y); v[4*i+2]=b2f(t.z); v[4*i+3]=b2f(t.w);
                }
            } else {
                const float* p = (const float*)Wv + (size_t)(n0 + srow)*HH + kc + skb;
                #pragma unroll
                for (int i = 0; i < 4; ++i) {
                    float4 t = *(const float4*)(p + 4*i);
                    v[4*i]=t.x; v[4*i+1]=t.y; v[4*i+2]=t.z; v[4*i+3]=t.w;
                }
            }
            #pragma unroll
            for (int i = 0; i < 4; ++i) {
                unsigned short h[4], l[4];
                #pragma unroll
                for (int j = 0; j < 4; ++j) splitf(v[4*i+j], h[j], l[j]);
                *(ushort4*)&Wh[srow][skb + 4*i] = make_ushort4(h[0], h[1], h[2], h[3]);
                if (ws) *(ushort4*)&Wl[srow][skb + 4*i] = make_ushort4(l[0], l[1], l[2], l[3]);
            }
        }
        __syncthreads();
        #pragma unroll
        for (int d = 0; d < 2; ++d) {
            const int kl = 32*d + quad*8;
            #pragma unroll
            for (int mt = 0; mt < 2; ++mt) {
                const int xr = 32*mi + 16*mt + l16;
                bf16x8 ah = *(const bf16x8*)&Xh[xr][kl];
                bf16x8 al;
                if (xs) al = *(const bf16x8*)&Xl[xr][kl];
                #pragma unroll
                for (int nt = 0; nt < 2; ++nt) {
                    const int wr = 32*ni + 16*nt + l16;
                    bf16x8 bh = *(const bf16x8*)&Wh[wr][kl];
                    acc[mt][nt] = MF(ah, bh, acc[mt][nt]);
                    if (xs) acc[mt][nt] = MF(al, bh, acc[mt][nt]);
                    if (ws) {
                        bf16x8 bl = *(const bf16x8*)&Wl[wr][kl];
                        acc[mt][nt] = MF(ah, bl, acc[mt][nt]);
                    }
                }
            }
        }
    }
    unsigned short* vtH = nullptr;
    if (mode == 4) { vtH = (unsigned short*)(cur ? S0w : S1w); }
    #pragma unroll
    for (int nt = 0; nt < 2; ++nt) {
        const int col = n0 + 32*ni + 16*nt + l16;
        const float bv = bbf ? b2f(((const unsigned short*)Bv)[col]) : ((const float*)Bv)[col];
        #pragma unroll
        for (int mt = 0; mt < 2; ++mt)
            #pragma unroll
            for (int e = 0; e < 4; ++e) {
                const int row = m0 + 32*mi + 16*mt + quad*4 + e;
                const float vv = acc[mt][nt][e] + bv;
                const size_t idx = (size_t)row*HH + col;
                if (mode == 0) outF[idx] = vv;
                else if (mode == 1) {
                    if (obf) ((unsigned short*)outExt)[idx] = f2b(vv);
                    else     ((float*)outExt)[idx] = vv;
                } else {
                    unsigned short h, l; splitf(vv, h, l);
                    const size_t t = ((size_t)(row >> 11) * HH + col) * SS + (row & 2047);
                    if (mode == 3) {
                        pKH[idx] = h; pKL[idx] = l;
                        pKTH[t] = h;  pKTL[t] = l;
                    } else {                       // mode 4: V transposed planes
                        vtH[t] = h; vtH[(size_t)NN*HH + t] = l;
                    }
                }
            }
    }
}

// ---------- MFMA flash attention, split-bf16, 2 blocks/CU ----------
template<bool FINAL>
__global__ __launch_bounds__(256, 2) void mfma_attn(
    float* __restrict__ S0w, float* __restrict__ S1w,
    const unsigned short* __restrict__ KH, const unsigned short* __restrict__ KL,
    const unsigned short* __restrict__ KTH, const unsigned short* __restrict__ KTL,
    Ctl* sc)
{
    if constexpr (!FINAL) { if (sc->conv) return; }
    const int cur = sc->cur;
    float* Scur = cur ? S1w : S0w;
    float* Out  = FINAL ? Scur : (cur ? S0w : S1w);
    const unsigned short* VTH = FINAL ? (const unsigned short*)(cur ? S0w : S1w) : KTH;
    const unsigned short* VTL = FINAL ? (VTH + (size_t)NN*HH) : KTL;

    __shared__ __align__(16) unsigned char UB[36864];
    __shared__ __align__(16) unsigned short SHl[32*520];
    __shared__ __align__(16) unsigned short Pth[32*72], Ptl[32*72];
    __shared__ __align__(16) float mld[32], lld[32], ald[32];
    __shared__ float redd[4], redo[4];
    unsigned short* KBH = (unsigned short*)UB;            // [64][136]
    unsigned short* KBL = KBH + 64*136;
    unsigned short* KTHs = (unsigned short*)UB;           // [128][72]
    unsigned short* KTLs = KTHs + 128*72;
    float* Sld = (float*)UB;                              // [32][68]

    const int tid = threadIdx.x;
    const int lane = tid & 63, w = tid >> 6;
    const int quad = lane >> 4, l16 = lane & 15;
    const int r = w & 1, s = w >> 1;

    const int bid = blockIdx.x;
    const int e8 = bid & 7;
    const int b = e8 >> 1;
    const int q0 = 32 * ((bid >> 3) + 32 * (e8 & 1));

    // ---- load state tile: hi frags to regs, lo plane to LDS ----
    bf16x8 ah[16];
    {
        const float* Qr = Scur + ((size_t)b*SS + q0 + 16*r + l16) * HH + quad*8;
        #pragma unroll
        for (int f = 0; f < 16; ++f) {
            float4 v0 = *(const float4*)(Qr + 32*f);
            float4 v1 = *(const float4*)(Qr + 32*f + 4);
            unsigned short h[8], l[8];
            splitf(v0.x,h[0],l[0]); splitf(v0.y,h[1],l[1]); splitf(v0.z,h[2],l[2]); splitf(v0.w,h[3],l[3]);
            splitf(v1.x,h[4],l[4]); splitf(v1.y,h[5],l[5]); splitf(v1.z,h[6],l[6]); splitf(v1.w,h[7],l[7]);
            bf16x8 af;
            #pragma unroll
            for (int j = 0; j < 8; ++j) af[j] = (short)h[j];
            ah[f] = af;
            if (s == 0) {
                unsigned short* d = &SHl[(16*r + l16)*520 + 32*f + quad*8];  // FIX: +quad*8
                *(ushort4*)(d)     = make_ushort4(l[0], l[1], l[2], l[3]);
                *(ushort4*)(d + 4) = make_ushort4(l[4], l[5], l[6], l[7]);
            }
        }
        if (tid < 32) { mld[tid] = -INFINITY; lld[tid] = 0.f; }
    }

    f32x4 O[16];
    #pragma unroll
    for (int i = 0; i < 16; ++i) O[i] = (f32x4){0.f, 0.f, 0.f, 0.f};

    const size_t bSSHH = (size_t)b * SS * HH;
    const size_t bHHSS = (size_t)b * HH * SS;

    const int key = tid >> 2, hs = (tid & 3) * 32;        // KB staging
    const int rw = tid >> 1, k1 = (tid & 1) * 32;         // KT staging

    for (int kt = 0; kt < SS/64; ++kt) {
        f32x4 sacc0 = (f32x4){0.f,0.f,0.f,0.f};
        f32x4 sacc1 = (f32x4){0.f,0.f,0.f,0.f};
        // ---- scores: 4 hid-chunks of 128 ----
        #pragma unroll
        for (int c = 0; c < 4; ++c) {
            __syncthreads();
            {
                const size_t g = bSSHH + (size_t)(kt*64 + key)*HH + c*128 + hs;
                unsigned short* dh = &KBH[key*136 + hs];
                unsigned short* dl = &KBL[key*136 + hs];
                #pragma unroll
                for (int i = 0; i < 4; ++i) {
                    *(uint4*)(dh + 8*i) = *(const uint4*)(KH + g + 8*i);
                    *(uint4*)(dl + 8*i) = *(const uint4*)(KL + g + 8*i);
                }
            }
            __syncthreads();
            #pragma unroll
            for (int kf = 0; kf < 4; ++kf) {
                bf16x8 alf = *(const bf16x8*)&SHl[(16*r + l16)*520 + c*128 + kf*32 + quad*8];
                const int c0 = kf*32 + quad*8;
                bf16x8 bh0 = *(const bf16x8*)&KBH[(32*s + l16)*136 + c0];
                bf16x8 bl0 = *(const bf16x8*)&KBL[(32*s + l16)*136 + c0];
                bf16x8 bh1 = *(const bf16x8*)&KBH[(32*s + 16 + l16)*136 + c0];
                bf16x8 bl1 = *(const bf16x8*)&KBL[(32*s + 16 + l16)*136 + c0];
                const bf16x8 a = ah[c*4 + kf];
                sacc0 = MF(a, bh0, sacc0); sacc0 = MF(alf, bh0, sacc0); sacc0 = MF(a, bl0, sacc0);
                sacc1 = MF(a, bh1, sacc1); sacc1 = MF(alf, bh1, sacc1); sacc1 = MF(a, bl1, sacc1);
            }
        }
        __syncthreads();                                   // KB dead -> Sld overlays
        #pragma unroll
        for (int e = 0; e < 4; ++e) {
            Sld[(16*r + quad*4 + e)*68 + 32*s + l16]      = sacc0[e] * SCALE_F;
            Sld[(16*r + quad*4 + e)*68 + 32*s + 16 + l16] = sacc1[e] * SCALE_F;
        }
        __syncthreads();
        // ---- online softmax: 8 threads/row over 64 keys ----
        {
            const int row = tid >> 3, sg = tid & 7;
            const float* sr = Sld + row*68 + sg*8;
            float4 x0 = *(const float4*)(sr);
            float4 x1 = *(const float4*)(sr + 4);
            float mt = fmaxf(fmaxf(fmaxf(x0.x,x0.y), fmaxf(x0.z,x0.w)),
                             fmaxf(fmaxf(x1.x,x1.y), fmaxf(x1.z,x1.w)));
            #pragma unroll
            for (int mk = 1; mk < 8; mk <<= 1) mt = fmaxf(mt, __shfl_xor(mt, mk, 8));
            const float mprev = mld[row];
            const float mnew = fmaxf(mprev, mt);
            float p[8];
            p[0]=__expf(x0.x-mnew); p[1]=__expf(x0.y-mnew); p[2]=__expf(x0.z-mnew); p[3]=__expf(x0.w-mnew);
            p[4]=__expf(x1.x-mnew); p[5]=__expf(x1.y-mnew); p[6]=__expf(x1.z-mnew); p[7]=__expf(x1.w-mnew);
            float ps = p[0]+p[1]+p[2]+p[3]+p[4]+p[5]+p[6]+p[7];
            #pragma unroll
            for (int mk = 1; mk < 8; mk <<= 1) ps += __shfl_xor(ps, mk, 8);
            const float alpha = __expf(mprev - mnew);
            if (sg == 0) { mld[row] = mnew; lld[row] = lld[row]*alpha + ps; ald[row] = alpha; }
            unsigned short h[8], l[8];
            #pragma unroll
            for (int i = 0; i < 8; ++i) splitf(p[i], h[i], l[i]);
            unsigned short* dh = &Pth[row*72 + sg*8];
            unsigned short* dl = &Ptl[row*72 + sg*8];
            *(ushort4*)(dh)     = make_ushort4(h[0],h[1],h[2],h[3]);
            *(ushort4*)(dh + 4) = make_ushort4(h[4],h[5],h[6],h[7]);
            *(ushort4*)(dl)     = make_ushort4(l[0],l[1],l[2],l[3]);
            *(ushort4*)(dl + 4) = make_ushort4(l[4],l[5],l[6],l[7]);
        }
        __syncthreads();
        // ---- rescale O, load P frags ----
        {
            const float4 av = *(const float4*)&ald[16*r + 4*quad];
            const float a4[4] = {av.x, av.y, av.z, av.w};
            #pragma unroll
            for (int i = 0; i < 16; ++i)
                #pragma unroll
                for (int e = 0; e < 4; ++e) O[i][e] *= a4[e];
        }
        bf16x8 pah[2], pal[2];
        #pragma unroll
        for (int kf = 0; kf < 2; ++kf) {
            pah[kf] = *(const bf16x8*)&Pth[(16*r + l16)*72 + kf*32 + quad*8];
            pal[kf] = *(const bf16x8*)&Ptl[(16*r + l16)*72 + kf*32 + quad*8];
        }
        // ---- PV: 4 chunks ----
        #pragma unroll
        for (int c = 0; c < 4; ++c) {
            __syncthreads();
            {
                const int hid = c*64 + (rw & 63) + 256*(rw >> 6);
                const size_t g = bHHSS + (size_t)hid*SS + (size_t)kt*64 + k1;
                unsigned short* dh = &KTHs[rw*72 + k1];
                unsigned short* dl = &KTLs[rw*72 + k1];
                #pragma unroll
                for (int i = 0; i < 4; ++i) {
                    *(uint4*)(dh + 8*i) = *(const uint4*)(VTH + g + 8*i);
                    *(uint4*)(dl + 8*i) = *(const uint4*)(VTL + g + 8*i);
                }
            }
            __syncthreads();
            #pragma unroll
            for (int nt = 0; nt < 4; ++nt) {
                const int rb = (64*s + 16*nt + l16)*72;
                #pragma unroll
                for (int kf = 0; kf < 2; ++kf) {
                    bf16x8 bh = *(const bf16x8*)&KTHs[rb + kf*32 + quad*8];
                    bf16x8 bl = *(const bf16x8*)&KTLs[rb + kf*32 + quad*8];
                    O[c*4+nt] = MF(pah[kf], bh, O[c*4+nt]);
                    O[c*4+nt] = MF(pal[kf], bh, O[c*4+nt]);
                    O[c*4+nt] = MF(pah[kf], bl, O[c*4+nt]);
                }
            }
        }
    }
    // ---- epilogue ----
    const float4 lv = *(const float4*)&lld[16*r + 4*quad];
    const float inv[4] = {1.f/lv.x, 1.f/lv.y, 1.f/lv.z, 1.f/lv.w};
    float pd = 0.f, po = 0.f;
    #pragma unroll
    for (int c = 0; c < 4; ++c)
        #pragma unroll
        for (int nt = 0; nt < 4; ++nt)
            #pragma unroll
            for (int e = 0; e < 4; ++e) {
                const int row = q0 + 16*r + quad*4 + e;
                const int col = 256*s + 64*c + 16*nt + l16;
                const float nv = O[c*4+nt][e] * inv[e];
                const size_t idx = (size_t)b*SS*HH + (size_t)row*HH + col;
                if constexpr (!FINAL) {
                    const float old = Scur[idx];
                    const float d = nv - old;
                    pd += d*d; po += old*old;
                }
                Out[idx] = nv;
            }
    if constexpr (!FINAL) {
        #pragma unroll
        for (int mk = 1; mk < 64; mk <<= 1) {
            pd += __shfl_xor(pd, mk, 64);
            po += __shfl_xor(po, mk, 64);
        }
        if (lane == 0) { redd[w] = pd; redo[w] = po; }
        __syncthreads();
        if (tid == 0) {
            atomicAdd(&sc->sum_d, redd[0] + redd[1] + redd[2] + redd[3]);
            atomicAdd(&sc->sum_o, redo[0] + redo[1] + redo[2] + redo[3]);
        }
    }
}

__global__ __launch_bounds__(64) void flag_update(Ctl* sc) {
    if (threadIdx.x != 0) return;
    if (sc->conv) return;
    sc->cur ^= 1;
    sc->iters += 1;
    const float delta = sqrtf(sc->sum_d) / (sqrtf(sc->sum_o) + 1e-8f);
    if (delta < THRESH) sc->conv = 1;
    sc->sum_d = 0.f; sc->sum_o = 0.f;
}

__global__ __launch_bounds__(64) void write_scalars(const Ctl* sc, void* outv) {
    if (threadIdx.x != 0) return;
    if (sc->bf[9]) {
        unsigned short* o = (unsigned short*)outv;
        o[(size_t)NN*HH]     = f2b((float)sc->iters);
        o[(size_t)NN*HH + 1] = f2b(sc->conv ? 1.0f : 0.0f);
    } else {
        float* o = (float*)outv;
        o[(size_t)NN*HH]     = (float)sc->iters;
        o[(size_t)NN*HH + 1] = sc->conv ? 1.0f : 0.0f;
    }
}

extern "C" void kernel_launch(void* const* d_in, const int* in_sizes, int n_in,
                              void* d_out, int out_size, void* d_ws, size_t ws_size,
                              hipStream_t stream)
{
    const void* x  = d_in[0];
    const void* Wq = d_in[1];
    const void* bq = d_in[2];
    const void* Wk = d_in[3];
    const void* bk = d_in[4];
    const void* Wv = d_in[5];
    const void* bv = d_in[6];
    const void* Wo = d_in[7];
    const void* bo = d_in[8];

    Ctl* sc = (Ctl*)d_ws;
    float* S0 = (float*)d_ws + CTL_FLOATS;                 // [NN,HH] fp32 state ping
    float* S1 = S0 + (size_t)NN*HH;                        // [NN,HH] fp32 state pong / VT planes
    unsigned short* KH  = (unsigned short*)(S1 + (size_t)NN*HH);
    unsigned short* KL  = KH  + (size_t)NN*HH;
    unsigned short* KTH = KL  + (size_t)NN*HH;
    unsigned short* KTL = KTH + (size_t)NN*HH;             // total ~67.1 MB (proven)

    const dim3 ggrid(NN/64, HH/64);   // 128 x 8
    const int  agrid = 256;           // 1D, XCD-swizzled

    detect_dtypes<<<9, 256, 0, stream>>>(x, Wq, bq, Wk, bk, Wv, bv, Wo, bo, sc);
    init_flags<<<1, 64, 0, stream>>>(sc);

    // Q projection -> S0 (fp32)
    mfma_gemm<<<ggrid, 256, 0, stream>>>(x, 0, Wq, 1, bq, 2, S0, nullptr,
                                         nullptr, nullptr, nullptr, nullptr, S0, S1, 0, sc);
    // K projection -> KH/KL + transposed KTH/KTL
    mfma_gemm<<<ggrid, 256, 0, stream>>>(x, 0, Wk, 3, bk, 4, nullptr, nullptr,
                                         KH, KL, KTH, KTL, S0, S1, 3, sc);

    for (int it = 0; it < 5; ++it) {
        mfma_attn<false><<<agrid, 256, 0, stream>>>(S0, S1, KH, KL, KTH, KTL, sc);
        flag_update<<<1, 64, 0, stream>>>(sc);
    }

    // V projection -> transposed planes into the dead state buffer buf[1^cur]
    mfma_gemm<<<ggrid, 256, 0, stream>>>(x, 0, Wv, 5, bv, 6, nullptr, nullptr,
                                         nullptr, nullptr, nullptr, nullptr, S0, S1, 4, sc);
    // Final readout attention (in-place on buf[cur], V from VT planes)
    mfma_attn<true><<<agrid, 256, 0, stream>>>(S0, S1, KH, KL, KTH, KTL, sc);
    // Output projection from buf[cur]
    mfma_gemm<<<ggrid, 256, 0, stream>>>(nullptr, -2, Wo, 7, bo, 8, nullptr, d_out,
                                         nullptr, nullptr, nullptr, nullptr, S0, S1, 1, sc);
    if (out_size >= (int)((size_t)NN*HH + 2))
        write_scalars<<<1, 64, 0, stream>>>(sc, d_out);
}